// Round 6
// baseline (78.561 us; speedup 1.0000x reference)
//
#include <hip/hip_runtime.h>
#include <cstdint>

static constexpr int BATCH = 64;
static constexpr int NPB   = 512 * 512;   // elements per batch
static constexpr int NCB   = 1024;        // 512 half-bins x 2 target classes
static constexpr int HBLK  = 16;          // blocks per batch

// d_ws layout in 32-bit words:
static constexpr int W_MINK = 0;      // 1024 uint: per-block min key
static constexpr int W_MAXK = 1024;   // 1024 uint: per-block max key
static constexpr int W_T1   = 2048;   // 64 uint: per-batch phase-1 tickets
static constexpr int W_T2   = 2112;   // 64 uint: per-batch phase-2 tickets
static constexpr int W_GH   = 4096;   // 64*1024 uint: per-batch global hists

typedef float f4 __attribute__((ext_vector_type(4)));

__device__ __forceinline__ uint32_t fkey(float f) {   // monotone float->uint key
  uint32_t u = __float_as_uint(f);
  return u ^ ((u & 0x80000000u) ? 0xFFFFFFFFu : 0x80000000u);
}
__device__ __forceinline__ float funkey(uint32_t k) {
  uint32_t u = (k & 0x80000000u) ? (k ^ 0x80000000u) : ~k;
  return __uint_as_float(u);
}
__device__ __forceinline__ float sigmoidf(float v) {  // precise: pmin/pmax/centers only
  if (v >= 0.0f) return 1.0f / (1.0f + expf(-v));
  float e = expf(v);
  return e / (1.0f + e);
}
__device__ __forceinline__ float fsig(float v) {      // fast: per-element binning only
  return __builtin_amdgcn_rcpf(1.0f + __expf(-v));
}

// Init: zero per-batch hists, tickets, out[0]. 64 blocks x 256 threads.
__global__ __launch_bounds__(256) void k_init(uint32_t* __restrict__ ws,
                                              float* __restrict__ out) {
  const int j = blockIdx.x;
  const int t = threadIdx.x;
  const uint4 z = {0u, 0u, 0u, 0u};
  reinterpret_cast<uint4*>(ws + W_GH + (size_t)j * NCB)[t] = z;
  if (j == 0) {
    if (t < 128) ws[W_T1 + t] = 0u;   // T1[64] + T2[64]
    if (t == 0) out[0] = 0.0f;
  }
}

// Fused: phase1 min/max -> per-batch spin barrier -> phase2 hist -> leader Otsu+IoU.
// 1024 blocks x 256 thr; ~45 VGPR / 16.9 KiB LDS => >=8 blocks/CU capacity vs 4 needed.
__global__ __launch_bounds__(256) void k_fused(const float* __restrict__ x,
                                               const float* __restrict__ tg,
                                               uint32_t* __restrict__ ws,
                                               float* __restrict__ out) {
  __shared__ uint32_t h[4 * NCB];        // 16 KiB: wave hist replicas, later Otsu scratch
  __shared__ float sPmin, sScale, sBinw;
  __shared__ int sFlag;
  const int t = threadIdx.x;
  const int g = blockIdx.x;
  const int b = g >> 4;
  const int blk = g & 15;
  const size_t base = (size_t)b * NPB + (size_t)blk * (NPB / 16);
  const float4* px = reinterpret_cast<const float4*>(x + base);

  // ---- phase 1: min/max of this block's slice ----
  float mn = INFINITY, mx = -INFINITY;
#pragma unroll
  for (int i = 0; i < 16; ++i) {
    float4 v = px[i * 256 + t];
    mn = fminf(mn, fminf(fminf(v.x, v.y), fminf(v.z, v.w)));
    mx = fmaxf(mx, fmaxf(fmaxf(v.x, v.y), fmaxf(v.z, v.w)));
  }
  for (int off = 32; off; off >>= 1) {
    mn = fminf(mn, __shfl_down(mn, off));
    mx = fmaxf(mx, __shfl_down(mx, off));
  }
  __shared__ float smn[4], smx[4];
  if ((t & 63) == 0) { smn[t >> 6] = mn; smx[t >> 6] = mx; }
  __syncthreads();
  if (t == 0) {
    mn = fminf(fminf(smn[0], smn[1]), fminf(smn[2], smn[3]));
    mx = fmaxf(fmaxf(smx[0], smx[1]), fmaxf(smx[2], smx[3]));
    // publish at LLC (device-scope atomics; no L2 dirty lines, no fences)
    atomicExch(&ws[W_MINK + g], fkey(mn));
    atomicExch(&ws[W_MAXK + g], fkey(mx));
    asm volatile("s_waitcnt vmcnt(0)" ::: "memory");   // keys visible BEFORE ticket
    __hip_atomic_fetch_add(&ws[W_T1 + b], 1u, __ATOMIC_RELAXED, __HIP_MEMORY_SCOPE_AGENT);
    // per-batch spin: all 1024 blocks co-resident (2x occupancy margin), deadlock-free
    while (__hip_atomic_load(&ws[W_T1 + b], __ATOMIC_RELAXED, __HIP_MEMORY_SCOPE_AGENT) < HBLK)
      __builtin_amdgcn_s_sleep(2);
  }
  __syncthreads();

  // ---- batch min/max -> pmin/scale ----
  uint32_t mk = 0xFFFFFFFFu, xk = 0u;
  if (t < 16) {
    mk = __hip_atomic_load(&ws[W_MINK + (b << 4) + t], __ATOMIC_RELAXED, __HIP_MEMORY_SCOPE_AGENT);
    xk = __hip_atomic_load(&ws[W_MAXK + (b << 4) + t], __ATOMIC_RELAXED, __HIP_MEMORY_SCOPE_AGENT);
  }
  for (int off = 8; off; off >>= 1) {
    mk = min(mk, (uint32_t)__shfl_down((int)mk, off));
    xk = max(xk, (uint32_t)__shfl_down((int)xk, off));
  }
  if (t == 0) {
    const float pmin = sigmoidf(funkey(mk));
    const float pmax = sigmoidf(funkey(xk));
    const float span = pmax - pmin;
    sPmin = pmin;
    sScale = (span > 0.0f) ? (512.0f / span) : 0.0f;   // == 2*(256/span) bit-exactly
    sBinw = span * (1.0f / 256.0f);                    // span/NBINS (pow2, exact)
  }
  const uint4 z = {0u, 0u, 0u, 0u};
  reinterpret_cast<uint4*>(h)[t]       = z;
  reinterpret_cast<uint4*>(h)[t + 256] = z;
  reinterpret_cast<uint4*>(h)[t + 512] = z;
  reinterpret_cast<uint4*>(h)[t + 768] = z;
  __syncthreads();

  // ---- phase 2: histogram (x re-read LLC-hot; tg nontemporal single-use stream) ----
  const float pmin = sPmin, scale = sScale;
  const uint32_t woff = (uint32_t)(t >> 6) << 10;
  const f4* pt = reinterpret_cast<const f4*>(tg + base);
#pragma unroll 4
  for (int i = 0; i < 16; ++i) {
    float4 v = px[i * 256 + t];
    f4 w = __builtin_nontemporal_load(pt + i * 256 + t);
#define PUT(a, c) { float fv = (fsig(a) - pmin) * scale;                  \
                    int idx = (int)fv;                                     \
                    idx = idx < 0 ? 0 : (idx > 511 ? 511 : idx);           \
                    idx += ((c) > 0.5f) ? 512 : 0;                         \
                    atomicAdd(&h[woff + idx], 1u); }
    PUT(v.x, w.x) PUT(v.y, w.y) PUT(v.z, w.z) PUT(v.w, w.w)
#undef PUT
  }
  __syncthreads();
  // merge replicas -> per-batch global hist via device atomics (at LLC, no fences)
  uint32_t* gh = ws + W_GH + (size_t)b * NCB;
#pragma unroll
  for (int j = 0; j < 4; ++j) {
    const int i = t + j * 256;
    const uint32_t v = h[i] + h[i + 1024] + h[i + 2048] + h[i + 3072];
    if (v) atomicAdd(&gh[i], v);
  }
  __syncthreads();                       // all waves drain vmcnt before barrier
  if (t == 0) {
    const uint32_t old = atomicAdd(&ws[W_T2 + b], 1u);
    sFlag = (old == HBLK - 1);
  }
  __syncthreads();
  if (!sFlag) return;                    // non-leader blocks done

  // ---- Otsu + IoU (last-arriving block per batch) ----
  uint32_t* hc  = h;                                    // 1024
  uint32_t* w1s = h + 1024;                             // 256
  float*    s1s = reinterpret_cast<float*>(h + 1280);   // 256
  float*    vv  = reinterpret_cast<float*>(h + 1536);   // 256
  int*      vi  = reinterpret_cast<int*>(h + 1792);     // 256
  unsigned long long* redL = reinterpret_cast<unsigned long long*>(h + 2048);  // 256 ull

#pragma unroll
  for (int j = 0; j < 4; ++j) {
    const int i = t + j * 256;
    hc[i] = __hip_atomic_load(&gh[i], __ATOMIC_RELAXED, __HIP_MEMORY_SCOPE_AGENT);
  }
  __syncthreads();
  const float binw = sBinw;
  const uint32_t a0 = hc[2 * t] + hc[2 * t + 512];
  const uint32_t a1 = hc[2 * t + 1] + hc[2 * t + 513];
  const uint32_t p0 = hc[2 * t + 512], p1 = hc[2 * t + 513];
  const uint32_t hk = a0 + a1;                        // reference 256-bin hist[t]
  const float ck = pmin + ((float)t + 0.5f) * binw;   // centers[t]
  w1s[t] = hk;
  s1s[t] = (float)hk * ck;
  for (int off = 1; off < 256; off <<= 1) {           // Hillis-Steele scans (w1 exact)
    __syncthreads();
    uint32_t wp = (t >= off) ? w1s[t - off] : 0u;
    float    sp = (t >= off) ? s1s[t - off] : 0.0f;
    __syncthreads();
    w1s[t] += wp; s1s[t] += sp;
  }
  __syncthreads();
  const uint32_t totW = w1s[255];
  const float totS = s1s[255];
  float v = -INFINITY;
  if (t < 255) {
    const float w1f = (float)w1s[t];
    const float w2f = (float)(totW - w1s[t]);
    const float m1 = s1s[t] / w1f;
    const float m2 = (totS - s1s[t]) / w2f;
    const float d = m1 - m2;
    v = (w1f * w2f) * (d * d);
  }
  vv[t] = v; vi[t] = t;
  for (int s = 128; s; s >>= 1) {        // argmax, first-occurrence tie-break
    __syncthreads();
    if (t < s) {
      const float vb = vv[t + s]; const int ib = vi[t + s];
      if (vb > vv[t] || (vb == vv[t] && ib < vi[t])) { vv[t] = vb; vi[t] = ib; }
    }
  }
  __syncthreads();
  const int J = 2 * vi[0] + 1;           // threshold = half-bin boundary index
  const uint32_t nb_p = ((2 * t) >= J ? a0 : 0u) + ((2 * t + 1) >= J ? a1 : 0u);
  const uint32_t ni_p = ((2 * t) >= J ? p0 : 0u) + ((2 * t + 1) >= J ? p1 : 0u);
  const uint32_t nt_p = p0 + p1;
  redL[t] = (unsigned long long)nb_p | ((unsigned long long)ni_p << 20) | ((unsigned long long)nt_p << 40);
  for (int s = 128; s; s >>= 1) {
    __syncthreads();
    if (t < s) redL[t] += redL[t + s];
  }
  __syncthreads();
  if (t == 0) {
    const unsigned long long P = redL[0];
    const float nb = (float)(uint32_t)(P & 0xFFFFFu);
    const float ni = (float)(uint32_t)((P >> 20) & 0xFFFFFu);
    const float nt = (float)(uint32_t)((P >> 40) & 0xFFFFFu);
    const float uni = nb + nt - ni;
    const float iou = (ni + 1.0f) / (uni + 1.0f);
    atomicAdd(out, iou * (1.0f / 64.0f));
  }
}

extern "C" void kernel_launch(void* const* d_in, const int* in_sizes, int n_in,
                              void* d_out, int out_size, void* d_ws, size_t ws_size,
                              hipStream_t stream) {
  const float* x  = (const float*)d_in[0];   // logits (64,1,512,512)
  const float* tg = (const float*)d_in[1];   // target (64,1,512,512)
  uint32_t* ws = (uint32_t*)d_ws;
  float* out = (float*)d_out;

  hipLaunchKernelGGL(k_init,  dim3(BATCH),        dim3(256), 0, stream, ws, out);
  hipLaunchKernelGGL(k_fused, dim3(BATCH * HBLK), dim3(256), 0, stream, x, tg, ws, out);
}

// Round 7
// 46.321 us; speedup vs baseline: 1.6960x; 1.6960x over previous
//
#include <hip/hip_runtime.h>
#include <cstdint>

static constexpr int BATCH = 64;
static constexpr int NPB   = 512 * 512;   // elements per batch
static constexpr int NCB   = 1024;        // 512 half-bins x 2 target classes
static constexpr int HBLK  = 16;          // blocks per batch

// d_ws layout in 32-bit words:
static constexpr int W_MINK = 0;      // 1024 uint: per-block min key
static constexpr int W_MAXK = 1024;   // 1024 uint: per-block max key
static constexpr int W_T1   = 2048;   // 64 tickets, 32-word (128 B) stride each
static constexpr int W_T2   = 4096;   // 64 tickets, 32-word stride
static constexpr int W_GH   = 8192;   // 64*1024 uint: per-batch global hists

typedef float f4 __attribute__((ext_vector_type(4)));

__device__ __forceinline__ uint32_t fkey(float f) {   // monotone float->uint key
  uint32_t u = __float_as_uint(f);
  return u ^ ((u & 0x80000000u) ? 0xFFFFFFFFu : 0x80000000u);
}
__device__ __forceinline__ float funkey(uint32_t k) {
  uint32_t u = (k & 0x80000000u) ? (k ^ 0x80000000u) : ~k;
  return __uint_as_float(u);
}
__device__ __forceinline__ float sigmoidf(float v) {  // precise: pmin/pmax/centers only
  if (v >= 0.0f) return 1.0f / (1.0f + expf(-v));
  float e = expf(v);
  return e / (1.0f + e);
}
__device__ __forceinline__ float fsig(float v) {      // fast: per-element binning only
  return __builtin_amdgcn_rcpf(1.0f + __expf(-v));
}
// System-scope relaxed load: emits sc0+sc1 -> always served from the LLC
// (coherence point), never a stale XCD L2 line. Safe for values that mutate
// during the kernel (tickets) and for cross-XCD published data.
__device__ __forceinline__ uint32_t llc_load(const uint32_t* p) {
  return __hip_atomic_load(p, __ATOMIC_RELAXED, __HIP_MEMORY_SCOPE_SYSTEM);
}

// Init: zero per-batch hist + tickets + out[0]. 64 blocks x 256 threads.
__global__ __launch_bounds__(256) void k_init(uint32_t* __restrict__ ws,
                                              float* __restrict__ out) {
  const int j = blockIdx.x;
  const int t = threadIdx.x;
  const uint4 z = {0u, 0u, 0u, 0u};
  reinterpret_cast<uint4*>(ws + W_GH + (size_t)j * NCB)[t] = z;   // 256 x 16B = 4 KiB row
  if (t < 32) { ws[W_T1 + j * 32 + t] = 0u; ws[W_T2 + j * 32 + t] = 0u; }
  if (j == 0 && t == 0) out[0] = 0.0f;
}

// Fused: phase1 min/max -> per-batch spin barrier (LLC poll) -> phase2 hist
//        -> last-arriver leader per batch: Otsu + IoU -> atomicAdd into out[0].
// 1024 blocks x 256 thr; 32 VGPR / 16.9 KiB LDS => 8 blocks/CU capacity vs 4 needed.
__global__ __launch_bounds__(256) void k_fused(const float* __restrict__ x,
                                               const float* __restrict__ tg,
                                               uint32_t* __restrict__ ws,
                                               float* __restrict__ out) {
  __shared__ uint32_t h[4 * NCB];        // 16 KiB: wave hist replicas, later Otsu scratch
  __shared__ float smn[4], smx[4];
  __shared__ float sPmin, sScale, sBinw;
  __shared__ int sFlag;
  const int t = threadIdx.x;
  const int g = blockIdx.x;
  const int b = g >> 4;
  const int blk = g & 15;
  const size_t base = (size_t)b * NPB + (size_t)blk * (NPB / 16);
  const float4* px = reinterpret_cast<const float4*>(x + base);

  // ---- phase 1: min/max of this block's slice ----
  float mn = INFINITY, mx = -INFINITY;
#pragma unroll
  for (int i = 0; i < 16; ++i) {
    float4 v = px[i * 256 + t];
    mn = fminf(mn, fminf(fminf(v.x, v.y), fminf(v.z, v.w)));
    mx = fmaxf(mx, fmaxf(fmaxf(v.x, v.y), fmaxf(v.z, v.w)));
  }
  for (int off = 32; off; off >>= 1) {
    mn = fminf(mn, __shfl_down(mn, off));
    mx = fmaxf(mx, __shfl_down(mx, off));
  }
  if ((t & 63) == 0) { smn[t >> 6] = mn; smx[t >> 6] = mx; }
  __syncthreads();

  // zero wave hist replicas while thread 0 publishes + spins
  const uint4 z = {0u, 0u, 0u, 0u};
  reinterpret_cast<uint4*>(h)[t]       = z;
  reinterpret_cast<uint4*>(h)[t + 256] = z;
  reinterpret_cast<uint4*>(h)[t + 512] = z;
  reinterpret_cast<uint4*>(h)[t + 768] = z;

  if (t == 0) {
    mn = fminf(fminf(smn[0], smn[1]), fminf(smn[2], smn[3]));
    mx = fmaxf(fmaxf(smx[0], smx[1]), fmaxf(smx[2], smx[3]));
    // publish at LLC via device-scope RMW (no dirty L2 lines, no fences)
    atomicExch(&ws[W_MINK + g], fkey(mn));
    atomicExch(&ws[W_MAXK + g], fkey(mx));
    asm volatile("s_waitcnt vmcnt(0)" ::: "memory");   // keys visible BEFORE ticket
    atomicAdd(&ws[W_T1 + b * 32], 1u);
    // per-batch spin: padded ticket line, system-scope poll (LLC, never stale L2)
    while (llc_load(&ws[W_T1 + b * 32]) < HBLK)
      __builtin_amdgcn_s_sleep(32);
  }
  __syncthreads();                       // barrier passed for the whole batch

  // ---- batch min/max -> pmin/scale ----
  uint32_t mk = 0xFFFFFFFFu, xk = 0u;
  if (t < 16) {
    mk = llc_load(&ws[W_MINK + (b << 4) + t]);
    xk = llc_load(&ws[W_MAXK + (b << 4) + t]);
  }
  for (int off = 8; off; off >>= 1) {
    mk = min(mk, (uint32_t)__shfl_down((int)mk, off));
    xk = max(xk, (uint32_t)__shfl_down((int)xk, off));
  }
  if (t == 0) {
    const float pmin = sigmoidf(funkey(mk));
    const float pmax = sigmoidf(funkey(xk));
    const float span = pmax - pmin;
    sPmin = pmin;
    sScale = (span > 0.0f) ? (512.0f / span) : 0.0f;   // == 2*(256/span) bit-exactly
    sBinw = span * (1.0f / 256.0f);                    // span/NBINS (pow2, exact)
  }
  __syncthreads();

  // ---- phase 2: histogram (x re-read LLC-hot; tg nontemporal single-use stream) ----
  const float pmin = sPmin, scale = sScale;
  const uint32_t woff = (uint32_t)(t >> 6) << 10;
  const f4* pt = reinterpret_cast<const f4*>(tg + base);
#pragma unroll 4
  for (int i = 0; i < 16; ++i) {
    float4 v = px[i * 256 + t];
    f4 w = __builtin_nontemporal_load(pt + i * 256 + t);
#define PUT(a, c) { float fv = (fsig(a) - pmin) * scale;                  \
                    int idx = (int)fv;                                     \
                    idx = idx < 0 ? 0 : (idx > 511 ? 511 : idx);           \
                    idx += ((c) > 0.5f) ? 512 : 0;                         \
                    atomicAdd(&h[woff + idx], 1u); }
    PUT(v.x, w.x) PUT(v.y, w.y) PUT(v.z, w.z) PUT(v.w, w.w)
#undef PUT
  }
  __syncthreads();
  // merge replicas -> per-batch global hist via device atomics (at LLC, no fences)
  uint32_t* gh = ws + W_GH + (size_t)b * NCB;
#pragma unroll
  for (int j = 0; j < 4; ++j) {
    const int i = t + j * 256;
    const uint32_t v = h[i] + h[i + 1024] + h[i + 2048] + h[i + 3072];
    if (v) atomicAdd(&gh[i], v);
  }
  __syncthreads();                       // every wave drained vmcnt before this barrier
  if (t == 0) {
    const uint32_t old = atomicAdd(&ws[W_T2 + b * 32], 1u);   // RMW ticket, no poll
    sFlag = (old == HBLK - 1);
  }
  __syncthreads();
  if (!sFlag) return;                    // non-leader blocks done

  // ---- Otsu + IoU (last-arriving block per batch) ----
  uint32_t* hc  = h;                                    // 1024
  uint32_t* w1s = h + 1024;                             // 256
  float*    s1s = reinterpret_cast<float*>(h + 1280);   // 256
  float*    vv  = reinterpret_cast<float*>(h + 1536);   // 256
  int*      vi  = reinterpret_cast<int*>(h + 1792);     // 256
  unsigned long long* redL = reinterpret_cast<unsigned long long*>(h + 2048);  // 256 ull

#pragma unroll
  for (int j = 0; j < 4; ++j) {
    const int i = t + j * 256;
    hc[i] = llc_load(&gh[i]);
  }
  __syncthreads();
  const float binw = sBinw;
  const uint32_t a0 = hc[2 * t] + hc[2 * t + 512];
  const uint32_t a1 = hc[2 * t + 1] + hc[2 * t + 513];
  const uint32_t p0 = hc[2 * t + 512], p1 = hc[2 * t + 513];
  const uint32_t hk = a0 + a1;                        // reference 256-bin hist[t]
  const float ck = pmin + ((float)t + 0.5f) * binw;   // centers[t]
  w1s[t] = hk;
  s1s[t] = (float)hk * ck;
  for (int off = 1; off < 256; off <<= 1) {           // Hillis-Steele scans (w1 exact)
    __syncthreads();
    uint32_t wp = (t >= off) ? w1s[t - off] : 0u;
    float    sp = (t >= off) ? s1s[t - off] : 0.0f;
    __syncthreads();
    w1s[t] += wp; s1s[t] += sp;
  }
  __syncthreads();
  const uint32_t totW = w1s[255];
  const float totS = s1s[255];
  float v = -INFINITY;
  if (t < 255) {
    const float w1f = (float)w1s[t];
    const float w2f = (float)(totW - w1s[t]);
    const float m1 = s1s[t] / w1f;
    const float m2 = (totS - s1s[t]) / w2f;
    const float d = m1 - m2;
    v = (w1f * w2f) * (d * d);
  }
  vv[t] = v; vi[t] = t;
  for (int s = 128; s; s >>= 1) {        // argmax, first-occurrence tie-break
    __syncthreads();
    if (t < s) {
      const float vb = vv[t + s]; const int ib = vi[t + s];
      if (vb > vv[t] || (vb == vv[t] && ib < vi[t])) { vv[t] = vb; vi[t] = ib; }
    }
  }
  __syncthreads();
  const int J = 2 * vi[0] + 1;           // threshold = half-bin boundary index
  const uint32_t nb_p = ((2 * t) >= J ? a0 : 0u) + ((2 * t + 1) >= J ? a1 : 0u);
  const uint32_t ni_p = ((2 * t) >= J ? p0 : 0u) + ((2 * t + 1) >= J ? p1 : 0u);
  const uint32_t nt_p = p0 + p1;
  redL[t] = (unsigned long long)nb_p | ((unsigned long long)ni_p << 20) | ((unsigned long long)nt_p << 40);
  for (int s = 128; s; s >>= 1) {
    __syncthreads();
    if (t < s) redL[t] += redL[t + s];
  }
  __syncthreads();
  if (t == 0) {
    const unsigned long long P = redL[0];
    const float nb = (float)(uint32_t)(P & 0xFFFFFu);
    const float ni = (float)(uint32_t)((P >> 20) & 0xFFFFFu);
    const float nt = (float)(uint32_t)((P >> 40) & 0xFFFFFu);
    const float uni = nb + nt - ni;
    const float iou = (ni + 1.0f) / (uni + 1.0f);
    atomicAdd(out, iou * (1.0f / 64.0f));
  }
}

extern "C" void kernel_launch(void* const* d_in, const int* in_sizes, int n_in,
                              void* d_out, int out_size, void* d_ws, size_t ws_size,
                              hipStream_t stream) {
  const float* x  = (const float*)d_in[0];   // logits (64,1,512,512)
  const float* tg = (const float*)d_in[1];   // target (64,1,512,512)
  uint32_t* ws = (uint32_t*)d_ws;
  float* out = (float*)d_out;

  hipLaunchKernelGGL(k_init,  dim3(BATCH),        dim3(256), 0, stream, ws, out);
  hipLaunchKernelGGL(k_fused, dim3(BATCH * HBLK), dim3(256), 0, stream, x, tg, ws, out);
}

// Round 8
// 33.678 us; speedup vs baseline: 2.3327x; 1.3754x over previous
//
#include <hip/hip_runtime.h>
#include <cstdint>

static constexpr int BATCH = 64;
static constexpr int NPB   = 512 * 512;   // elements per batch
static constexpr int NFB   = 2048;        // fixed fine bins in sigmoid space [0,1]
static constexpr int PBLK  = 8;           // pass blocks per batch (512 total)
static constexpr int ELB   = NPB / PBLK;  // 32768 elements per block (max u16-1 safe)

// d_ws layout in 32-bit words (~4.2 MB, all fully rewritten every launch):
static constexpr int W_BMIN = 0;      // 512 floats: per-block min of x
static constexpr int W_BMAX = 512;    // 512 floats: per-block max of x
static constexpr int W_PART = 1024;   // 512 blocks x 2048 words (u16-packed 4096 counts)

__device__ __forceinline__ float sigmoidf(float v) {  // precise: pmin/pmax only
  if (v >= 0.0f) return 1.0f / (1.0f + expf(-v));
  float e = expf(v);
  return e / (1.0f + e);
}
__device__ __forceinline__ float fsig(float v) {      // fast: per-element binning only
  return __builtin_amdgcn_rcpf(1.0f + __expf(-v));
}

// Pass: ONE visit of x and tg. Per block: min/max of x + fixed-grid joint histogram
// (2048 sigmoid bins x 2 target classes), 2 LDS replicas, u16-packed partial out.
__global__ __launch_bounds__(256) void k_pass(const float* __restrict__ x,
                                              const float* __restrict__ tg,
                                              uint32_t* __restrict__ ws,
                                              float* __restrict__ out) {
  __shared__ uint32_t h[2 * 2 * NFB];    // 2 replicas x 4096 counters = 32 KiB
  const int t = threadIdx.x;
  const int g = blockIdx.x;
  if (g == 0 && t == 0) out[0] = 0.0f;   // zeroed each launch before finalize runs
  // zero replicas
  const uint4 z = {0u, 0u, 0u, 0u};
#pragma unroll
  for (int j = 0; j < 8; ++j) reinterpret_cast<uint4*>(h)[t + j * 256] = z;
  __syncthreads();

  const int b = g >> 3;
  const int blk = g & 7;
  const size_t base = (size_t)b * NPB + (size_t)blk * ELB;
  const float4* px = reinterpret_cast<const float4*>(x + base);
  const float4* pt = reinterpret_cast<const float4*>(tg + base);
  const uint32_t woff = (uint32_t)(t >> 7) << 12;   // wave-pair replica (0 or 4096)

  float mn = INFINITY, mx = -INFINITY;
#pragma unroll 4
  for (int i = 0; i < 32; ++i) {
    float4 v = px[i * 256 + t];
    float4 w = pt[i * 256 + t];
    mn = fminf(mn, fminf(fminf(v.x, v.y), fminf(v.z, v.w)));
    mx = fmaxf(mx, fmaxf(fmaxf(v.x, v.y), fmaxf(v.z, v.w)));
#define PUT(a, c) { int idx = (int)(fsig(a) * 2048.0f);                   \
                    idx = idx > 2047 ? 2047 : idx;                        \
                    idx += ((c) > 0.5f) ? 2048 : 0;                       \
                    atomicAdd(&h[woff + idx], 1u); }
    PUT(v.x, w.x) PUT(v.y, w.y) PUT(v.z, w.z) PUT(v.w, w.w)
#undef PUT
  }
  // block min/max
  for (int off = 32; off; off >>= 1) {
    mn = fminf(mn, __shfl_down(mn, off));
    mx = fmaxf(mx, __shfl_down(mx, off));
  }
  __shared__ float smn[4], smx[4];
  if ((t & 63) == 0) { smn[t >> 6] = mn; smx[t >> 6] = mx; }
  __syncthreads();
  if (t == 0) {
    float* wsf = reinterpret_cast<float*>(ws);
    wsf[W_BMIN + g] = fminf(fminf(smn[0], smn[1]), fminf(smn[2], smn[3]));
    wsf[W_BMAX + g] = fmaxf(fmaxf(smx[0], smx[1]), fmaxf(smx[2], smx[3]));
  }
  // merge replicas, pack 2 u16 counts per word (count <= 32768 fits), plain store
  uint32_t* gp = ws + W_PART + (size_t)g * (2 * NFB / 2);
#pragma unroll
  for (int j = 0; j < 8; ++j) {
    const int w = t + j * 256;                       // word index 0..2047
    const uint32_t c0 = h[2 * w] + h[2 * w + 4096];
    const uint32_t c1 = h[2 * w + 1] + h[2 * w + 1 + 4096];
    gp[w] = c0 | (c1 << 16);
  }
}

// Finalize: one block per batch. Merge 8 partials -> fine hist; exact pmin/pmax;
// remap fine bins to the reference 512-halfbin grid; Otsu argmax; suffix counts; IoU.
__global__ __launch_bounds__(256) void k_finalize(uint32_t* __restrict__ ws,
                                                  float* __restrict__ out) {
  __shared__ uint32_t fj[2 * NFB];       // 4096 fine counts (16 KiB)
  __shared__ uint32_t h256[256];
  __shared__ uint32_t w1s[256];
  __shared__ float s1s[256];
  __shared__ float vv[256];
  __shared__ int vi[256];
  __shared__ unsigned long long redL[256];
  __shared__ float sPmin, sScale, sBinw;
  const int b = blockIdx.x;
  const int t = threadIdx.x;
  const float* wsf = reinterpret_cast<const float*>(ws);

  // merge 8 u16-packed partials
#pragma unroll
  for (int j = 0; j < 8; ++j) {
    const int w = t + j * 256;
    uint32_t a0 = 0, a1 = 0;
#pragma unroll
    for (int p = 0; p < PBLK; ++p) {
      const uint32_t v = ws[W_PART + (size_t)(b * PBLK + p) * NFB + w];
      a0 += v & 0xFFFFu;
      a1 += v >> 16;
    }
    fj[2 * w] = a0;
    fj[2 * w + 1] = a1;
  }
  h256[t] = 0u;
  // batch min/max from 8 per-block values
  float mnv = (t < PBLK) ? wsf[W_BMIN + b * PBLK + t] : INFINITY;
  float mxv = (t < PBLK) ? wsf[W_BMAX + b * PBLK + t] : -INFINITY;
  for (int off = 4; off; off >>= 1) {
    mnv = fminf(mnv, __shfl_down(mnv, off));
    mxv = fmaxf(mxv, __shfl_down(mxv, off));
  }
  if (t == 0) {
    const float pmin = sigmoidf(mnv);
    const float pmax = sigmoidf(mxv);
    const float span = pmax - pmin;
    sPmin = pmin;
    sScale = (span > 0.0f) ? (512.0f / span) : 0.0f;   // halfbin scale (=2*scale256)
    sBinw = span * (1.0f / 256.0f);                    // span/NBINS (pow2, exact)
  }
  __syncthreads();
  const float pmin = sPmin, scale = sScale, binw = sBinw;

  // fine -> 512-halfbin remap via bin midpoint; build 256-bin Otsu hist
#define CIDX(k) ({ const float rep = ((float)(k) + 0.5f) * (1.0f / 2048.0f);  \
                   int ci = (int)((rep - pmin) * scale);                      \
                   ci = ci < 0 ? 0 : (ci > 511 ? 511 : ci); ci; })
#pragma unroll
  for (int j = 0; j < 8; ++j) {
    const int w = t + j * 256;           // word -> fine idx 2w, 2w+1
    const int i0 = 2 * w, i1 = 2 * w + 1;
    const int k0 = i0 & (NFB - 1), k1 = i1 & (NFB - 1);
    if (fj[i0]) atomicAdd(&h256[CIDX(k0) >> 1], fj[i0]);
    if (fj[i1]) atomicAdd(&h256[CIDX(k1) >> 1], fj[i1]);
  }
  __syncthreads();

  // Otsu over 256 bins (reference arithmetic)
  const uint32_t hk = h256[t];
  const float ck = pmin + ((float)t + 0.5f) * binw;   // centers[t]
  w1s[t] = hk;
  s1s[t] = (float)hk * ck;
  for (int off = 1; off < 256; off <<= 1) {           // Hillis-Steele scans (w1 exact)
    __syncthreads();
    uint32_t wp = (t >= off) ? w1s[t - off] : 0u;
    float    sp = (t >= off) ? s1s[t - off] : 0.0f;
    __syncthreads();
    w1s[t] += wp; s1s[t] += sp;
  }
  __syncthreads();
  const uint32_t totW = w1s[255];
  const float totS = s1s[255];
  float v = -INFINITY;
  if (t < 255 && w1s[t] > 0u && totW > w1s[t]) {
    const float w1f = (float)w1s[t];
    const float w2f = (float)(totW - w1s[t]);
    const float m1 = s1s[t] / w1f;
    const float m2 = (totS - s1s[t]) / w2f;
    const float d = m1 - m2;
    v = (w1f * w2f) * (d * d);
  }
  vv[t] = v; vi[t] = t;
  for (int s = 128; s; s >>= 1) {        // argmax, first-occurrence tie-break
    __syncthreads();
    if (t < s) {
      const float vb = vv[t + s]; const int ib = vi[t + s];
      if (vb > vv[t] || (vb == vv[t] && ib < vi[t])) { vv[t] = vb; vi[t] = ib; }
    }
  }
  __syncthreads();
  const int J = 2 * vi[0] + 1;           // threshold = halfbin boundary index

  // suffix counts over fine bins whose halfbin index >= J
  uint32_t nb_p = 0, ni_p = 0, nt_p = 0;
#pragma unroll
  for (int j = 0; j < 8; ++j) {
    const int w = t + j * 256;
#pragma unroll
    for (int e = 0; e < 2; ++e) {
      const int idx = 2 * w + e;
      const uint32_t cnt = fj[idx];
      const int cls = idx >> 11;         // 0..1 (NFB=2048)
      const int k = idx & (NFB - 1);
      nt_p += cls ? cnt : 0u;
      if (CIDX(k) >= J) { nb_p += cnt; ni_p += cls ? cnt : 0u; }
    }
  }
#undef CIDX
  redL[t] = (unsigned long long)nb_p | ((unsigned long long)ni_p << 20) | ((unsigned long long)nt_p << 40);
  for (int s = 128; s; s >>= 1) {
    __syncthreads();
    if (t < s) redL[t] += redL[t + s];
  }
  __syncthreads();
  if (t == 0) {
    const unsigned long long P = redL[0];
    const float nb = (float)(uint32_t)(P & 0xFFFFFu);
    const float ni = (float)(uint32_t)((P >> 20) & 0xFFFFFu);
    const float nt = (float)(uint32_t)((P >> 40) & 0xFFFFFu);
    const float uni = nb + nt - ni;
    const float iou = (ni + 1.0f) / (uni + 1.0f);
    atomicAdd(out, iou * (1.0f / 64.0f));
  }
}

extern "C" void kernel_launch(void* const* d_in, const int* in_sizes, int n_in,
                              void* d_out, int out_size, void* d_ws, size_t ws_size,
                              hipStream_t stream) {
  const float* x  = (const float*)d_in[0];   // logits (64,1,512,512)
  const float* tg = (const float*)d_in[1];   // target (64,1,512,512)
  uint32_t* ws = (uint32_t*)d_ws;
  float* out = (float*)d_out;

  hipLaunchKernelGGL(k_pass,     dim3(BATCH * PBLK), dim3(256), 0, stream, x, tg, ws, out);
  hipLaunchKernelGGL(k_finalize, dim3(BATCH),        dim3(256), 0, stream, ws, out);
}